// Round 2
// baseline (703.734 us; speedup 1.0000x reference)
//
#include <hip/hip_runtime.h>
#include <cstdint>
#include <cstddef>

#define NPTS 8192
#define NUM_CLASSES 5
#define XCOLS 10          // 3 coords + batch + feat + 5 seg
#define EPS2 225.0f
#define MIN_PTS 5
#define NGROUPS 10
#define NW 128            // 64-bit words per adjacency row
#define BIGC 0x3fffffff
#define JT 1024           // j-points staged per block in k_adj
#define WPB 16            // adjacency words per block (JT/64)

// ---------------- setup: pack coords+p2, group, init deg/parent ----------------
__global__ void k_setup(const float* __restrict__ x, float4* __restrict__ q,
                        int* __restrict__ grp, int* __restrict__ deg,
                        int* __restrict__ parent) {
    int i = blockIdx.x * blockDim.x + threadIdx.x;
    if (i >= NPTS) return;
    const float* r = x + (size_t)i * XCOLS;
    float px = r[0], py = r[1], pz = r[2];
    int b = (int)r[3];
    float best = r[5]; int bc = 0;
    #pragma unroll
    for (int c = 1; c < NUM_CLASSES; c++) {
        float v = r[5 + c];
        if (v > best) { best = v; bc = c; }   // strict > keeps first max (jnp.argmax)
    }
    q[i] = make_float4(px, py, pz, px*px + py*py + pz*pz);
    grp[i] = b * NUM_CLASSES + bc;
    deg[i] = 0;        // ws is poisoned 0xAA every call
    parent[i] = i;
}

// ---------------- adjacency: bit-column build ----------------
// grid = 128 row-tiles x 8 column-slices. block = 256 threads = 4 waves.
// lane l owns row rt*64+l; wave v builds words v*4..v*4+3 of this slice.
// j-points staged in LDS; reads are wave-uniform -> broadcast (conflict-free).
__global__ void __launch_bounds__(256) k_adj(
        const float4* __restrict__ q, const int* __restrict__ grp,
        unsigned long long* __restrict__ adj, int* __restrict__ deg) {
    __shared__ float4 qs[JT];
    __shared__ int    gs[JT];
    int rt = blockIdx.x >> 3;       // 0..127 row tile
    int wq = blockIdx.x & 7;        // 0..7 column slice
    int tid = threadIdx.x;
    int j0 = wq * JT;
    #pragma unroll
    for (int t = tid; t < JT; t += 256) {
        qs[t] = q[j0 + t];
        gs[t] = grp[j0 + t];
    }
    __syncthreads();

    int lane = tid & 63, wv = tid >> 6;
    int i = rt * 64 + lane;
    float4 qi = q[i];
    int gi = grp[i];
    int dpart = 0;

    #pragma unroll
    for (int k = 0; k < 4; k++) {
        int wl = wv * 4 + k;          // local word 0..15
        int base = wl * 64;
        unsigned int lo = 0, hi = 0;
        #pragma unroll 8
        for (int t = 0; t < 32; t++) {
            float4 qj = qs[base + t];
            int gj = gs[base + t];
            float d2 = qi.w + qj.w - 2.0f * (qi.x*qj.x + qi.y*qj.y + qi.z*qj.z);
            bool a = (gi == gj) && (d2 < EPS2);
            lo |= (a ? 1u : 0u) << t;
        }
        #pragma unroll 8
        for (int t = 0; t < 32; t++) {
            float4 qj = qs[base + 32 + t];
            int gj = gs[base + 32 + t];
            float d2 = qi.w + qj.w - 2.0f * (qi.x*qj.x + qi.y*qj.y + qi.z*qj.z);
            bool a = (gi == gj) && (d2 < EPS2);
            hi |= (a ? 1u : 0u) << t;
        }
        unsigned long long m = ((unsigned long long)hi << 32) | (unsigned long long)lo;
        adj[(size_t)i * NW + wq * WPB + wl] = m;
        dpart += __popcll(m);
    }
    atomicAdd(&deg[i], dpart);
}

// ---------------- lock-free union-find ----------------
__device__ __forceinline__ int uf_find(int* p, int x) {
    int px = __hip_atomic_load(&p[x], __ATOMIC_RELAXED, __HIP_MEMORY_SCOPE_AGENT);
    while (px != x) {
        int ppx = __hip_atomic_load(&p[px], __ATOMIC_RELAXED, __HIP_MEMORY_SCOPE_AGENT);
        // path halving: ppx is always an ancestor of x (ancestors are stable)
        __hip_atomic_store(&p[x], ppx, __ATOMIC_RELAXED, __HIP_MEMORY_SCOPE_AGENT);
        x = px; px = ppx;
    }
    return x;
}

// one wave per row; hook-to-smaller-root => component root = min core index,
// matching the reference's serial min-label semantics.
__global__ void __launch_bounds__(256) k_union(
        const unsigned long long* __restrict__ adj,
        const int* __restrict__ deg, int* __restrict__ parent) {
    int wave = (blockIdx.x * blockDim.x + threadIdx.x) >> 6;
    int lane = threadIdx.x & 63;
    int i = wave;
    if (i >= NPTS) return;
    if (deg[i] < MIN_PTS) return;            // wave-uniform: not core
    #pragma unroll
    for (int h = 0; h < 2; h++) {
        int w = lane + h * 64;
        unsigned long long bits = adj[(size_t)i * NW + w];
        int base = w * 64;
        // keep only j > i (each core-core edge unioned once)
        if (base + 63 <= i) bits = 0;
        else if (base <= i) bits &= ~((1ull << (i - base + 1)) - 1ull);
        while (bits) {
            int b = __ffsll((long long)bits) - 1;
            bits &= bits - 1;
            int j = base + b;
            if (deg[j] < MIN_PTS) continue;  // j must be core
            int u = i, v = j;
            while (true) {
                u = uf_find(parent, u);
                v = uf_find(parent, v);
                if (u == v) break;
                int big = u > v ? u : v;
                int small = u + v - big;
                if (atomicCAS(&parent[big], big, small) == big) break;
                u = big; v = small;
            }
        }
    }
}

// ---------------- per-group rank of representatives ----------------
// one wave per group; rep <=> core && parent[j]==j (roots are fixpoints)
__global__ void k_rank(const int* __restrict__ grp, const int* __restrict__ deg,
                       const int* __restrict__ parent, int* __restrict__ cidrep) {
    int g = blockIdx.x;
    int lane = threadIdx.x;
    int running = 0;
    for (int w = 0; w < NW; w++) {
        int j = w * 64 + lane;
        bool isr = (deg[j] >= MIN_PTS) && (parent[j] == j) && (grp[j] == g);
        unsigned long long mask = __ballot(isr);
        if (isr) {
            unsigned long long below = mask & ((1ull << lane) - 1ull);
            cidrep[j] = running + __popcll(below);
        }
        running += __popcll(mask);
    }
}

// ---------------- ccid: cluster id per core point (BIG for non-core) ----------------
__global__ void k_ccid(const int* __restrict__ deg, const int* __restrict__ parent,
                       const int* __restrict__ cidrep, int* __restrict__ ccid) {
    int i = blockIdx.x * blockDim.x + threadIdx.x;
    if (i >= NPTS) return;
    if (deg[i] >= MIN_PTS) {
        int x = i;
        int px = parent[x];               // plain loads fine post-kernel-boundary
        while (px != x) { x = px; px = parent[x]; }
        ccid[i] = cidrep[x];
    } else {
        ccid[i] = BIGC;
    }
}

// ---------------- final labels + clustered output ----------------
// one wave per row
__global__ void __launch_bounds__(256) k_final(
        const unsigned long long* __restrict__ adj,
        const int* __restrict__ deg, const int* __restrict__ ccid,
        const float* __restrict__ x, float* __restrict__ out) {
    int wave = (blockIdx.x * blockDim.x + threadIdx.x) >> 6;
    int lane = threadIdx.x & 63;
    int i = wave;
    if (i >= NPTS) return;
    int m = BIGC;
    #pragma unroll
    for (int wh = 0; wh < 2; wh++) {
        int w = lane + wh * 64;
        unsigned long long bits = adj[(size_t)i * NW + w];
        int base = w * 64;
        while (bits) {
            int b = __ffsll((long long)bits) - 1;
            bits &= bits - 1;
            int cj = ccid[base + b];
            m = (cj < m) ? cj : m;
        }
    }
    #pragma unroll
    for (int off = 32; off > 0; off >>= 1) {
        int o = __shfl_down(m, off);
        m = (o < m) ? o : m;
    }
    if (lane == 0) {
        int label = (deg[i] >= MIN_PTS) ? ccid[i] : ((m < BIGC) ? m : -1);
        out[i] = (float)label;
        const float* r = x + (size_t)i * XCOLS;
        float* o = out + NPTS + (size_t)i * 5;
        bool keep = label >= 0;
        #pragma unroll
        for (int c = 0; c < 5; c++) o[c] = keep ? r[c] : 0.0f;
    }
}

extern "C" void kernel_launch(void* const* d_in, const int* in_sizes, int n_in,
                              void* d_out, int out_size, void* d_ws, size_t ws_size,
                              hipStream_t stream) {
    const float* x = (const float*)d_in[0];
    float* out = (float*)d_out;
    char* ws = (char*)d_ws;

    // workspace layout (same 8.68 MB footprint as R1)
    float4* q    = (float4*)(ws);                         // 131072 B
    int* grp     = (int*)(ws + 131072);                   // 32768
    int* deg     = (int*)(ws + 163840);                   // 32768
    int* parent  = (int*)(ws + 196608);                   // 32768
    int* cidrep  = (int*)(ws + 229376);                   // 32768
    int* ccid    = (int*)(ws + 262144);                   // 32768
    unsigned long long* adj = (unsigned long long*)(ws + 294912);  // 8 MB

    k_setup<<<NPTS / 256, 256, 0, stream>>>(x, q, grp, deg, parent);
    k_adj<<<128 * 8, 256, 0, stream>>>(q, grp, adj, deg);
    k_union<<<NPTS / 4, 256, 0, stream>>>(adj, deg, parent);
    k_rank<<<NGROUPS, 64, 0, stream>>>(grp, deg, parent, cidrep);
    k_ccid<<<NPTS / 256, 256, 0, stream>>>(deg, parent, cidrep, ccid);
    k_final<<<NPTS / 4, 256, 0, stream>>>(adj, deg, ccid, x, out);
}

// Round 3
// 187.910 us; speedup vs baseline: 3.7451x; 3.7451x over previous
//
#include <hip/hip_runtime.h>
#include <cstdint>
#include <cstddef>

#define NPTS 8192
#define NUM_CLASSES 5
#define XCOLS 10          // 3 coords + batch + feat + 5 seg
#define EPS2 225.0f
#define MIN_PTS 5
#define NGROUPS 10
#define BIGC 0x3fffffff
#define ECAP 1000000      // edge capacity (expected ~53k)

#define RT_ROWS 1024      // rows per k_adj block
#define JT 128            // cols (j-points) staged per k_adj block
#define RPT 4             // rows per thread

// ---------------- setup: pack coords+p2, group, init deg/bmin/ecnt ----------------
__global__ void k_setup(const float* __restrict__ x, float4* __restrict__ q,
                        int* __restrict__ grp, int* __restrict__ deg,
                        int* __restrict__ bmin, unsigned int* __restrict__ ecnt) {
    int i = blockIdx.x * blockDim.x + threadIdx.x;
    if (i == 0) *ecnt = 0u;
    if (i >= NPTS) return;
    const float* r = x + (size_t)i * XCOLS;
    float px = r[0], py = r[1], pz = r[2];
    int b = (int)r[3];
    float best = r[5]; int bc = 0;
    #pragma unroll
    for (int c = 1; c < NUM_CLASSES; c++) {
        float v = r[5 + c];
        if (v > best) { best = v; bc = c; }   // strict > keeps first max (jnp.argmax)
    }
    q[i] = make_float4(px, py, pz, px*px + py*py + pz*pz);
    grp[i] = b * NUM_CLASSES + bc;
    deg[i] = 1;          // self-adjacency (d2=0 < EPS2, same group)
    bmin[i] = BIGC;
}

// ---------------- adjacency -> packed edge list (j>i only) + degree ----------------
// grid = 8 row-tiles x 64 col-slices; block = 256 threads; thread owns 4 rows
// (stride 256). j-points staged in LDS, read wave-uniform (broadcast).
__global__ void __launch_bounds__(256) k_adj(
        const float4* __restrict__ q, const int* __restrict__ grp,
        unsigned int* __restrict__ edges, unsigned int* __restrict__ ecnt,
        int* __restrict__ deg) {
    int rt = blockIdx.x >> 6;        // 0..7
    int cs = blockIdx.x & 63;        // 0..63
    int i0 = rt * RT_ROWS;
    int j0 = cs * JT;
    if (j0 + JT - 1 <= i0) return;   // whole block strictly lower-triangle: no j>i

    __shared__ float4 qs[JT];
    __shared__ int    gs[JT];
    int tid = threadIdx.x;
    if (tid < JT) { qs[tid] = q[j0 + tid]; gs[tid] = grp[j0 + tid]; }
    __syncthreads();

    int lane = tid & 63;
    float4 qi[RPT]; int gi[RPT]; int irow[RPT];
    #pragma unroll
    for (int r = 0; r < RPT; r++) {
        irow[r] = i0 + tid + 256 * r;
        qi[r] = q[irow[r]];
        gi[r] = grp[irow[r]];
    }

    #pragma unroll
    for (int w = 0; w < JT / 64; w++) {
        int jbase = j0 + w * 64;
        unsigned int lo[RPT], hi[RPT];
        #pragma unroll
        for (int r = 0; r < RPT; r++) { lo[r] = 0u; hi[r] = 0u; }
        for (int t = 0; t < 32; t++) {
            float4 qj = qs[w * 64 + t]; int gj = gs[w * 64 + t];   // broadcast
            #pragma unroll
            for (int r = 0; r < RPT; r++) {
                float d2 = qi[r].w + qj.w - 2.0f * (qi[r].x*qj.x + qi[r].y*qj.y + qi[r].z*qj.z);
                bool a = (gi[r] == gj) && (d2 < EPS2);
                lo[r] |= a ? (1u << t) : 0u;
            }
        }
        for (int t = 0; t < 32; t++) {
            float4 qj = qs[w * 64 + 32 + t]; int gj = gs[w * 64 + 32 + t];
            #pragma unroll
            for (int r = 0; r < RPT; r++) {
                float d2 = qi[r].w + qj.w - 2.0f * (qi[r].x*qj.x + qi[r].y*qj.y + qi[r].z*qj.z);
                bool a = (gi[r] == gj) && (d2 < EPS2);
                hi[r] |= a ? (1u << t) : 0u;
            }
        }
        // mask to j>i, count
        unsigned long long bits[RPT]; int rowc[RPT]; int cnt = 0;
        #pragma unroll
        for (int r = 0; r < RPT; r++) {
            unsigned long long b = ((unsigned long long)hi[r] << 32) | (unsigned long long)lo[r];
            int d = irow[r] - jbase;
            unsigned long long m;
            if (d < 0) m = ~0ull;
            else if (d >= 63) m = 0ull;
            else m = ~((2ull << d) - 1ull);
            b &= m;
            bits[r] = b;
            rowc[r] = __popcll(b);
            cnt += rowc[r];
        }
        // wave-aggregated append
        int off = cnt;
        #pragma unroll
        for (int dd = 1; dd < 64; dd <<= 1) {
            int o = __shfl_up(off, dd);
            if (lane >= dd) off += o;
        }
        int tot = __shfl(off, 63);
        int excl = off - cnt;
        int base = 0;
        if (tot > 0) {
            if (lane == 63) base = (int)atomicAdd(ecnt, (unsigned int)tot);
            base = __shfl(base, 63);
        }
        int p = base + excl;
        #pragma unroll
        for (int r = 0; r < RPT; r++) {
            if (rowc[r] > 0) {
                atomicAdd(&deg[irow[r]], rowc[r]);
                unsigned long long b = bits[r];
                while (b) {
                    int bb = __ffsll((unsigned long long)b) - 1;
                    b &= b - 1;
                    int j = jbase + bb;
                    if (p < ECAP) edges[p] = ((unsigned int)irow[r] << 13) | (unsigned int)j;
                    p++;
                    atomicAdd(&deg[j], 1);
                }
            }
        }
    }
}

// ---------------- LDS union-find helpers ----------------
__device__ __forceinline__ int lfind(volatile int* p, int x) {
    while (true) {
        int px = p[x];
        if (px == x) return x;
        int pp = p[px];
        if (pp == px) return px;
        p[x] = pp;            // path halving; monotone-decreasing, race-safe
        x = pp;
    }
}

// ---------------- mega: union-find + rank + ccid, single block ----------------
__global__ void __launch_bounds__(1024) k_mega(
        const unsigned int* __restrict__ edges, const unsigned int* __restrict__ ecnt,
        const int* __restrict__ deg, const int* __restrict__ grp,
        int* __restrict__ gcid, int* __restrict__ ccid) {
    __shared__ int spar[NPTS];                    // 32 KB
    __shared__ unsigned char sgrp[NPTS];          // 8 KB
    __shared__ unsigned long long corebm[NPTS/64];// 1 KB
    int tid = threadIdx.x;
    unsigned int Eu = *ecnt;
    int E = (Eu > (unsigned)ECAP) ? ECAP : (int)Eu;

    for (int i = tid; i < NPTS; i += 1024) { spar[i] = i; sgrp[i] = (unsigned char)grp[i]; }
    for (int w = tid; w < NPTS/64; w += 1024) corebm[w] = 0ull;
    __syncthreads();
    for (int i = tid; i < NPTS; i += 1024)
        if (deg[i] >= MIN_PTS) atomicOr(&corebm[i >> 6], 1ull << (i & 63));
    __syncthreads();

    auto corebit = [&](int x) -> bool { return (corebm[x >> 6] >> (x & 63)) & 1ull; };

    // union pass: exact connectivity, order-independent, root = min index
    for (int e = tid; e < E; e += 1024) {
        unsigned int pk = edges[e];
        int u = (int)(pk >> 13), v = (int)(pk & 8191u);
        if (!corebit(u) || !corebit(v)) continue;
        u = lfind(spar, u); v = lfind(spar, v);
        while (u != v) {
            int big = u > v ? u : v;
            int sml = u + v - big;
            int old = atomicCAS(&spar[big], big, sml);
            if (old == big) break;
            u = lfind(spar, old); v = lfind(spar, sml);
        }
    }
    __syncthreads();
    // flatten core nodes to roots
    for (int i = tid; i < NPTS; i += 1024)
        if (corebit(i)) spar[i] = lfind(spar, i);
    __syncthreads();
    // rank reps per group: waves 0..9 handle groups 0..9
    int g = tid >> 6, lane = tid & 63;
    if (g < NGROUPS) {
        int running = 0;
        for (int w = 0; w < NPTS / 64; w++) {
            int j = w * 64 + lane;
            bool isr = corebit(j) && (spar[j] == j) && ((int)sgrp[j] == g);
            unsigned long long mask = __ballot(isr);
            if (isr) gcid[j] = running + __popcll(mask & ((1ull << lane) - 1ull));
            running += __popcll(mask);
        }
    }
    __syncthreads();   // also fences the gcid global writes block-wide
    for (int i = tid; i < NPTS; i += 1024)
        ccid[i] = corebit(i) ? gcid[spar[i]] : BIGC;
}

// ---------------- border: min core-neighbor cid via edge list ----------------
__global__ void k_border(const unsigned int* __restrict__ edges,
                         const unsigned int* __restrict__ ecnt,
                         const int* __restrict__ ccid, int* __restrict__ bmin) {
    unsigned int Eu = *ecnt;
    int E = (Eu > (unsigned)ECAP) ? ECAP : (int)Eu;
    int stride = gridDim.x * blockDim.x;
    for (int e = blockIdx.x * blockDim.x + threadIdx.x; e < E; e += stride) {
        unsigned int pk = edges[e];
        int u = (int)(pk >> 13), v = (int)(pk & 8191u);
        int cu = ccid[u], cv = ccid[v];
        if (cu == BIGC && cv != BIGC) atomicMin(&bmin[u], cv);
        if (cv == BIGC && cu != BIGC) atomicMin(&bmin[v], cu);
    }
}

// ---------------- final labels + clustered output ----------------
__global__ void k_final(const int* __restrict__ ccid, const int* __restrict__ bmin,
                        const float* __restrict__ x, float* __restrict__ out) {
    int i = blockIdx.x * blockDim.x + threadIdx.x;
    if (i >= NPTS) return;
    int c = ccid[i];
    int lbl = (c != BIGC) ? c : ((bmin[i] < BIGC) ? bmin[i] : -1);
    out[i] = (float)lbl;
    const float* r = x + (size_t)i * XCOLS;
    float* o = out + NPTS + (size_t)i * 5;
    bool keep = lbl >= 0;
    #pragma unroll
    for (int c5 = 0; c5 < 5; c5++) o[c5] = keep ? r[c5] : 0.0f;
}

extern "C" void kernel_launch(void* const* d_in, const int* in_sizes, int n_in,
                              void* d_out, int out_size, void* d_ws, size_t ws_size,
                              hipStream_t stream) {
    const float* x = (const float*)d_in[0];
    float* out = (float*)d_out;
    char* ws = (char*)d_ws;

    // workspace layout (~4.3 MB)
    float4* q          = (float4*)(ws);                  // 131072 B
    int* grp           = (int*)(ws + 131072);            // 32768
    int* deg           = (int*)(ws + 163840);            // 32768
    int* bmin          = (int*)(ws + 196608);            // 32768
    int* ccid          = (int*)(ws + 229376);            // 32768
    int* gcid          = (int*)(ws + 262144);            // 32768
    unsigned int* ecnt = (unsigned int*)(ws + 294912);   // 128
    unsigned int* edges= (unsigned int*)(ws + 295040);   // 4 MB

    k_setup <<<NPTS / 256, 256, 0, stream>>>(x, q, grp, deg, bmin, ecnt);
    k_adj   <<<8 * 64, 256, 0, stream>>>(q, grp, edges, ecnt, deg);
    k_mega  <<<1, 1024, 0, stream>>>(edges, ecnt, deg, grp, gcid, ccid);
    k_border<<<128, 256, 0, stream>>>(edges, ecnt, ccid, bmin);
    k_final <<<NPTS / 256, 256, 0, stream>>>(ccid, bmin, x, out);
}